// Round 8
// baseline (941.119 us; speedup 1.0000x reference)
//
#include <hip/hip_runtime.h>

// ---------------- constants ----------------
#define T_ENC 64
#define T_DEC 99

// fp8 e4m3 weight workspace (BYTES), fragment-permuted, uniform 6 slots/layer:
// phase blob = 4 layers x 6 slots; slot s: 0..2 = h-side gates r/z/n, 3..5 = x-side
// gates r/z/n.
// R6/R8: GRU gate weights pre-scaled at convert time: r/z gates by log2(e),
// n gate by 2*log2(e) -> every epilogue exp() is one compiler-emitted v_exp_f32
// (2^x native). R8 lesson: do NOT hand-write v_exp_f32 in inline asm -- the
// TRANS result-use hazard is invisible to the compiler through INLINEASM and
// produced garbage (R7 fail: h saturated to fp8-max 448 then NaN). exp2f() is
// hazard-safe; fmaxf(x,-40) bounds the arg (no overflow anywhere) + kills NaN.
// MX K=128 slot layout (all slots EXCEPT layer-0 x-side):
//   slot[w][lane][b] (8*64*32 = 16384 BYTES): byte b (0..31) of lane (quad,ln) =
//   W[g*128 + w*16 + ln][quad*32 + b]   (scaled 16x16x128 B-layout, 32 B/lane)
// OLD K=32 layout ONLY for layer-0 x-side (wih0 zero-padded, ks=0 only):
//   slot[w][ks][lane][e]: byte e of lane = W[g*128+w*16+ln][ks*32+quad*8+e]
#define SLOT    16384
#define PH_BLOB 393216          // 24 slots
#define O_LIN1  786432          // 1 slot (lin1 B-frags, UNSCALED)
#define W_TOTAL 802816

#define L2E  1.4426950408889634f
#define L2E2 2.8853900817779268f

// output layout (f32 elements)
#define DEC_OUT_OFF 0
#define DEC_HID_OFF 1638400
#define ENC_OUT_OFF 3735552
#define ENC_HID_OFF 37289984
#define LOSS_OFF    39387136

typedef float f32x4 __attribute__((ext_vector_type(4)));
typedef int   v8i  __attribute__((ext_vector_type(8)));
typedef long  v4l  __attribute__((ext_vector_type(4)));

__device__ __forceinline__ v8i as8i(v4l x) {
  union { v4l l; v8i i; } u; u.l = x; return u.i;
}

// Empty-asm register tie: forces the loaded weight fragments to stay resident
// (R1 lesson: without it the compiler sank the loads into the t-loop).
__device__ __forceinline__ void keep(v4l &x) { asm volatile("" : "+v"(x)); }
__device__ __forceinline__ void keep(long &x) { asm volatile("" : "+v"(x)); }

// 2^(-x), hazard-safe (compiler-emitted v_exp_f32, neg folds to src modifier).
// fmaxf bounds the exp2 arg to <=40 (2^40=1.1e12: no downstream overflow) AND
// kills NaN (fmaxf(NaN,-40) = -40). Makes the gate math unconditionally finite.
__device__ __forceinline__ float exp2n(float x) {
  return exp2f(-fmaxf(x, -40.f));
}

// non-scaled K=32 fp8 MFMA (layer-0 x-side only)
#define MFMA8(a, b, c) __builtin_amdgcn_mfma_f32_16x16x32_fp8_fp8((a), (b), (c), 0, 0, 0)
// MX-scaled K=128 fp8 MFMA, scale byte 0x7F (=2^0) on both operands, fmt 0 = e4m3
#define MFMAS(a, b, c) \
  __builtin_amdgcn_mfma_scale_f32_16x16x128_f8f6f4(as8i(a), as8i(b), (c), 0, 0, 0, 127, 0, 127)

__device__ __forceinline__ unsigned f2fp8pk(float a, float b) {
  return (unsigned)__builtin_amdgcn_cvt_pk_fp8_f32(a, b, 0, false);
}

// ---------------- weight fp32 -> fp8 fragment-permute (+log2e baking) ----------
__device__ __forceinline__ float cw_value(int i,
    const float* ewih0, const float* ewhh0, const float* ewih, const float* ewhh,
    const float* dwih0, const float* dwhh0, const float* dwih, const float* dwhh,
    const float* lin1w) {
  if (i < O_LIN1) {
    const int ph = i / PH_BLOB;
    const int li = i % PH_BLOB;
    const float* wih0 = ph ? dwih0 : ewih0;
    const float* whh0 = ph ? dwhh0 : ewhh0;
    const float* wih  = ph ? dwih  : ewih;
    const float* whh  = ph ? dwhh  : ewhh;
    const int l = li / (6 * SLOT);
    const int r6 = li % (6 * SLOT);
    const int s = r6 / SLOT, r = r6 % SLOT;
    const int g = (s < 3) ? s : (s - 3);
    const float sc = (g == 2) ? L2E2 : L2E;   // n gate folds tanh's *2 too
    if (s >= 3 && l == 0) {
      const int w = r >> 11, ks = (r >> 9) & 3, lane = (r >> 3) & 63, e = r & 7;
      const int quad = lane >> 4, ln = lane & 15;
      const int row = g * 128 + w * 16 + ln;
      const int col = ks * 32 + quad * 8 + e;
      return (col < 4) ? sc * wih0[row * 4 + col] : 0.f;
    } else {
      const int w = r >> 11, lane = (r >> 5) & 63, b = r & 31;
      const int quad = lane >> 4, ln = lane & 15;
      const int row = g * 128 + w * 16 + ln;
      const int col = quad * 32 + b;
      return sc * ((s < 3) ? ((l == 0) ? whh0[row * 128 + col]
                                       : whh[(l - 1) * 49152 + row * 128 + col])
                           : wih[(l - 1) * 49152 + row * 128 + col]);
    }
  } else {
    const int r = i - O_LIN1;
    const int w = r >> 11, lane = (r >> 5) & 63, b = r & 31;
    const int quad = lane >> 4, ln = lane & 15;
    return lin1w[(w * 16 + ln) * 128 + quad * 32 + b];
  }
}

__global__ void convert_weights(const float* __restrict__ ewih0, const float* __restrict__ ewhh0,
                                const float* __restrict__ ewih, const float* __restrict__ ewhh,
                                const float* __restrict__ dwih0, const float* __restrict__ dwhh0,
                                const float* __restrict__ dwih, const float* __restrict__ dwhh,
                                const float* __restrict__ lin1w, unsigned char* __restrict__ wb,
                                float* __restrict__ out) {
  const int gid = blockIdx.x * 256 + threadIdx.x;
  if (gid == 0) out[LOSS_OFF] = 0.f;
  const int i0 = gid * 4;
  if (i0 >= W_TOTAL) return;
  unsigned w = 0;
#pragma unroll
  for (int k = 0; k < 4; k++) {
    float v = cw_value(i0 + k, ewih0, ewhh0, ewih, ewhh, dwih0, dwhh0, dwih, dwhh, lin1w);
    w |= (f2fp8pk(v, v) & 0xFFu) << (k * 8);
  }
  *(unsigned*)(wb + i0) = w;
}

// ---------------- main persistent kernel ----------------
// grid = 256 blocks (M=16 batch rows, 1 block/CU), block = 512 threads (8 waves).
// Layer-wavefront (R3): cells (t,l) on anti-diagonal d=t+l in ONE barrier
// interval (171 intervals). Trans diet (R6, hazard-fixed R8):
//  (a) log2e baked into weights/biases -> each exp is one v_exp_f32
//  (b) r/z reciprocals paired per element: 2 rcp -> 1 rcp + 3 mul
//  (c) n reciprocals paired across element pairs
//  (d) all exp2 args clamped >= -40 (exp2n): finite + NaN-proof by construction.
// Trans/element: 6 -> 4.5.
__global__ __launch_bounds__(512, 2) void gru_seq2seq(
    const float* __restrict__ inp, const float* __restrict__ tgt,
    const float* __restrict__ enc_bih, const float* __restrict__ enc_bhh,
    const float* __restrict__ dec_bih, const float* __restrict__ dec_bhh,
    const float* __restrict__ lin1_b, const float* __restrict__ lin2_w,
    const float* __restrict__ lin2_b, const unsigned char* __restrict__ wb,
    float* __restrict__ out) {
  const int tid = threadIdx.x;
  const int wave = tid >> 6;
  const int lane = tid & 63;
  const int ln = lane & 15;
  const int quad = lane >> 4;
  const int b0 = blockIdx.x * 16;
  const int j = (wave << 4) + ln;

  __shared__ __align__(16) unsigned char hb8[2][4][16][128];  // fp8 h [parity][l][m][swz k]
  __shared__ __align__(16) unsigned char xt8[2][16][128];     // fp8 x-tile (K=128 padded)
  __shared__ __align__(16) unsigned char trash[2048];         // sink for invalid-cell writes
  __shared__ float bsum[4][2][128];                           // (bih+bhh)*L2E for r,z
  __shared__ float bnn[4][2][128];                            // bin*L2E2, bhn*L2E2
  __shared__ float lin1bs[128];
  __shared__ __align__(16) float lin2ws[4][132];
  __shared__ float lin2bs[4];
  __shared__ __align__(16) float relu_s[2][16][132];          // double-buffered (pipeline stage)

  for (int i = tid; i < 2 * 4 * 16 * 128; i += 512) ((unsigned char*)hb8)[i] = 0;
  for (int i = tid; i < 2 * 16 * 128; i += 512) ((unsigned char*)xt8)[i] = 0;
  if (tid < 128) lin1bs[tid] = lin1_b[tid];
  { int e = tid >> 7, k = tid & 127; lin2ws[e][k] = lin2_w[e * 128 + k]; }
  if (tid < 4) lin2bs[tid] = lin2_b[tid];

  // fp32 h master, register-resident (thread-private: m=quad*4+r, col j)
  float hreg[4][4];
#pragma unroll
  for (int l = 0; l < 4; l++)
#pragma unroll
    for (int r = 0; r < 4; r++) hreg[l][r] = 0.f;

  float loss_local = 0.f;

  // decoder_output[:, 0, :] = inp[:, 0, :]
  if (tid < 64) {
    int m = tid >> 2, e = tid & 3;
    out[DEC_OUT_OFF + (b0 + m) * 400 + e] = inp[(b0 + m) * 256 + e];
  }

  const int fofs32 = wave * 2048 + lane * 32;
  const int fofs8  = wave * 2048 + lane * 8;

  v4l w1v = *(const v4l*)(wb + O_LIN1 + fofs32);
  keep(w1v);

#pragma unroll 1
  for (int ph = 0; ph < 2; ph++) {
    const float* bih = ph ? dec_bih : enc_bih;
    const float* bhh = ph ? dec_bhh : enc_bhh;
    {  // per-phase biases -> LDS (pre-scaled: r/z by L2E, n by L2E2)
      int l = tid >> 7, jj = tid & 127;
      bsum[l][0][jj] = L2E * (bih[l * 384 + jj] + bhh[l * 384 + jj]);
      bsum[l][1][jj] = L2E * (bih[l * 384 + 128 + jj] + bhh[l * 384 + 128 + jj]);
      bnn[l][0][jj] = L2E2 * bih[l * 384 + 256 + jj];
      bnn[l][1][jj] = L2E2 * bhh[l * 384 + 256 + jj];
    }
    // step-0 input for both phases: inp[:, 0, :] -> xt8[0] (read at d=0, p=0)
    if (tid < 64) {
      int m = tid >> 2, e = tid & 3;
      xt8[0][m][(m << 3) | e] =
          (unsigned char)(f2fp8pk(inp[(b0 + m) * 256 + e], 0.f) & 0xFF);
    }
    __syncthreads();

    // ---- per-phase REGISTER-RESIDENT fp8 weights (K=128 frags) ----
    const unsigned char* PB = wb + ph * PH_BLOB;
    v4l whv[4][3];  // h-side [l][gate]
    v4l wxv[3][3];  // x-side [l-1][gate], layers 1..3
    long wx0f[3];   // x-side layer 0, OLD layout ks=0 only
#pragma unroll
    for (int l = 0; l < 4; l++)
#pragma unroll
      for (int g = 0; g < 3; g++) {
        whv[l][g] = *(const v4l*)(PB + l * 6 * SLOT + g * SLOT + fofs32);
        keep(whv[l][g]);
      }
#pragma unroll
    for (int l = 1; l < 4; l++)
#pragma unroll
      for (int g = 0; g < 3; g++) {
        wxv[l - 1][g] = *(const v4l*)(PB + l * 6 * SLOT + (3 + g) * SLOT + fofs32);
        keep(wxv[l - 1][g]);
      }
#pragma unroll
    for (int g = 0; g < 3; g++) {
      wx0f[g] = *(const long*)(PB + (3 + g) * SLOT + fofs8);
      keep(wx0f[g]);
    }

    const float l1b = lin1bs[j];
    const int T = ph ? T_DEC : T_ENC;
    const int Dtot = ph ? (T_DEC + 5) : (T_ENC + 3);

#pragma unroll 1
    for (int d = 0; d < Dtot; d++) {
      const int p = d & 1;
      const unsigned char* hprev = &hb8[1 - p][0][0][0];  // [l][16][128] blob, parity 1-p

      // ======== 4 wavefront cells, one basic block, lazy A-frag reuse ========
      v4l Fprev;  // h-frags of layer l-1 (== x-side frags of cell l)
      long x0f;   // layer-0 x frag
      {
        const unsigned char* xb = &xt8[p][0][0] + ln * 128;
        x0f = *(const long*)(xb + ((quad ^ ln) << 3));
      }
#pragma unroll
      for (int l = 0; l < 4; l++) {
        const int t = d - l;
        const bool valid = (t >= 0) && (t < T);
        // load this layer's h-frags (reused as next cell's x-frags)
        v4l Fl;
        {
          const unsigned char* ahb = hprev + l * 2048 + ln * 128;
#pragma unroll
          for (int i4 = 0; i4 < 4; i4++)
            Fl[i4] = *(const long*)(ahb + ((((quad * 4 + i4) ^ ln) << 3)));
        }
        // bias-seeded accumulators (biases pre-scaled by L2E/L2E2)
        const float brl = bsum[l][0][j], bzl = bsum[l][1][j];
        const float binl = bnn[l][0][j], bhnl = bnn[l][1][j];
        f32x4 ar  = {brl, brl, brl, brl};
        f32x4 az  = {bzl, bzl, bzl, bzl};
        f32x4 ani = {binl, binl, binl, binl};
        f32x4 anh = {bhnl, bhnl, bhnl, bhnl};
        // h-side
        ar  = MFMAS(Fl, whv[l][0], ar);
        az  = MFMAS(Fl, whv[l][1], az);
        anh = MFMAS(Fl, whv[l][2], anh);
        // x-side
        if (l > 0) {
          ar  = MFMAS(Fprev, wxv[l - 1][0], ar);
          az  = MFMAS(Fprev, wxv[l - 1][1], az);
          ani = MFMAS(Fprev, wxv[l - 1][2], ani);
        } else {
          ar  = MFMA8(x0f, wx0f[0], ar);
          az  = MFMA8(x0f, wx0f[1], az);
          ani = MFMA8(x0f, wx0f[2], ani);
        }
        Fprev = Fl;  // becomes x-side of cell l+1 (and lin1 input at l=3)
        // ---- epilogue: trans-lean gates (4.5 trans/element), NaN-proof ----
        float zg4[4], en4[4], hnv[4];
#pragma unroll
        for (int r = 0; r < 4; r++) {
          const float er = exp2n(ar[r]);           // e^-x, arg clamped
          const float ez = exp2n(az[r]);
          const float Ar = 1.f + er, Az = 1.f + ez;
          const float R = __builtin_amdgcn_rcpf(Ar * Az);   // <= (1+2^40)^2: finite
          const float rg = Az * R;              // 1/(1+er)
          zg4[r] = Ar * R;                      // 1/(1+ez)
          const float xn = ani[r] + rg * anh[r];
          en4[r] = exp2n(xn);                   // e^-2y, <= 2^40
        }
#pragma unroll
        for (int rp = 0; rp < 2; rp++) {
          const float e0 = en4[2 * rp], e1 = en4[2 * rp + 1];
          const float D0 = 1.f + e0, D1 = 1.f + e1;
          const float R = __builtin_amdgcn_rcpf(D0 * D1);   // <= 1.2e24: finite
          const float ng0 = (1.f - e0) * (D1 * R);
          const float ng1 = (1.f - e1) * (D0 * R);
          {
            const int r = 2 * rp;
            const float hp = hreg[l][r];
            const float hn = ng0 + zg4[r] * (hp - ng0);
            hreg[l][r] = valid ? hn : hp;
            hnv[r] = hn;
          }
          {
            const int r = 2 * rp + 1;
            const float hp = hreg[l][r];
            const float hn = ng1 + zg4[r] * (hp - ng1);
            hreg[l][r] = valid ? hn : hp;
            hnv[r] = hn;
          }
        }
        {  // fp8 re-quantized h -> hb8[p][l], or trash when cell invalid
          unsigned pkA = f2fp8pk(hnv[0], hnv[1]);
          unsigned pkB = f2fp8pk(hnv[2], hnv[3]);
          unsigned char* hw = valid ? &hb8[p][l][0][0] : &trash[0];
          const int m0 = quad * 4;
#pragma unroll
          for (int r = 0; r < 4; r++) {
            const int m = m0 + r;
            const unsigned pk = (r < 2) ? pkA : pkB;
            hw[m * 128 + ((((j >> 3) ^ m) << 3) | (j & 7))] =
                (unsigned char)((pk >> ((r & 1) * 8)) & 0xFF);
          }
        }
      }  // cells

      // ======== deferred global stores (read hreg; uniform guards) ========
      if (!ph) {
        const int t3 = d - 3;  // cell (t3,3) finished this interval
        if (t3 >= 0) {
#pragma unroll
          for (int r = 0; r < 4; r++) {
            const int m = quad * 4 + r;
            out[ENC_OUT_OFF + ((b0 + m) * 64 + t3) * 128 + j] = hreg[3][r];
          }
        }
#pragma unroll
        for (int ll = 0; ll < 4; ll++)
          if (d == T_ENC - 1 + ll) {  // cell (63,ll) finished this interval
#pragma unroll
            for (int r = 0; r < 4; r++) {
              const int m = quad * 4 + r;
              out[ENC_HID_OFF + (ll * 4096 + b0 + m) * 128 + j] = hreg[ll][r];
            }
          }
      } else {
#pragma unroll
        for (int ll = 0; ll < 4; ll++)
          if (d == T_DEC - 1 + ll) {  // cell (98,ll) finished this interval
#pragma unroll
            for (int r = 0; r < 4; r++) {
              const int m = quad * 4 + r;
              out[DEC_HID_OFF + (ll * 4096 + b0 + m) * 128 + j] = hreg[ll][r];
            }
          }
      }

      // ======== x prefetch for step d+1 (read at interval d+1 from xt8[1-p]) ========
      if ((d + 1) < T && tid < 64) {
        int m = tid >> 2, e = tid & 3;
        float xv = ph ? tgt[(b0 + m) * 400 + (d + 1) * 4 + e]
                      : inp[(b0 + m) * 256 + (d + 1) * 4 + e];
        xt8[1 - p][m][(m << 3) | e] = (unsigned char)(f2fp8pk(xv, 0.f) & 0xFF);
      }

      // ======== decoder pipeline tails: lin1 (stage d-4), lin2 (stage d-5) ========
      if (ph) {
        const int t1 = d - 4;
        if (t1 >= 0 && t1 < T_DEC) {
          // h3[t1] written by cell (t1,3) at interval d-1 -> parity 1-p == Fprev
          f32x4 a1 = {l1b, l1b, l1b, l1b};
          a1 = MFMAS(Fprev, w1v, a1);
#pragma unroll
          for (int r = 0; r < 4; r++) {
            const int m = quad * 4 + r;
            const float v = a1[r];
            relu_s[p][m][j] = v > 0.f ? v : 0.f;
          }
        }
        const int t2 = d - 5;
        if (t2 >= 0) {  // t2 <= 98 guaranteed (d <= 103)
          const int m2 = tid >> 5, e2 = (tid >> 3) & 3, kg = tid & 7;
          const float4* rs = (const float4*)&relu_s[1 - p][m2][kg * 16];
          const float4* ws = (const float4*)&lin2ws[e2][kg * 16];
          float a0 = 0.f, a1p = 0.f;
#pragma unroll
          for (int q = 0; q < 4; q += 2) {
            float4 r0 = rs[q], w0 = ws[q];
            float4 r1 = rs[q + 1], w1 = ws[q + 1];
            a0 += r0.x * w0.x + r0.y * w0.y + r0.z * w0.z + r0.w * w0.w;
            a1p += r1.x * w1.x + r1.y * w1.y + r1.z * w1.z + r1.w * w1.w;
          }
          float acc = a0 + a1p;
          acc += __shfl_down(acc, 4);
          acc += __shfl_down(acc, 2);
          acc += __shfl_down(acc, 1);
          if (kg == 0) {
            acc += lin2bs[e2];
            const int oidx = (b0 + m2) * 400 + (t2 + 1) * 4 + e2;
            out[DEC_OUT_OFF + oidx] = acc;
            const float d2 = acc - tgt[oidx];
            loss_local += d2 * d2;
          }
        }
      }

      __syncthreads();
    }  // d
  }  // phase

  // ---- loss reduction ----
  loss_local *= (1.f / 16384.f);  // mean over (B=4096, E=4)
#pragma unroll
  for (int off = 32; off; off >>= 1) loss_local += __shfl_down(loss_local, off);
  if (lane == 0) atomicAdd(&out[LOSS_OFF], loss_local);
}

// ---------------- launch ----------------
extern "C" void kernel_launch(void* const* d_in, const int* in_sizes, int n_in,
                              void* d_out, int out_size, void* d_ws, size_t ws_size,
                              hipStream_t stream) {
  const float* inp      = (const float*)d_in[0];
  const float* tgt      = (const float*)d_in[1];
  const float* enc_wih0 = (const float*)d_in[2];
  const float* enc_whh0 = (const float*)d_in[3];
  const float* enc_wih  = (const float*)d_in[4];
  const float* enc_whh  = (const float*)d_in[5];
  const float* enc_bih  = (const float*)d_in[6];
  const float* enc_bhh  = (const float*)d_in[7];
  const float* dec_wih0 = (const float*)d_in[8];
  const float* dec_whh0 = (const float*)d_in[9];
  const float* dec_wih  = (const float*)d_in[10];
  const float* dec_whh  = (const float*)d_in[11];
  const float* dec_bih  = (const float*)d_in[12];
  const float* dec_bhh  = (const float*)d_in[13];
  const float* lin1_w   = (const float*)d_in[14];
  const float* lin1_b   = (const float*)d_in[15];
  const float* lin2_w   = (const float*)d_in[16];
  const float* lin2_b   = (const float*)d_in[17];
  unsigned char* wb = (unsigned char*)d_ws;
  float* out = (float*)d_out;

  hipLaunchKernelGGL(convert_weights, dim3((W_TOTAL / 4 + 255) / 256), dim3(256), 0, stream,
                     enc_wih0, enc_whh0, enc_wih, enc_whh, dec_wih0, dec_whh0, dec_wih,
                     dec_whh, lin1_w, wb, out);
  hipLaunchKernelGGL(gru_seq2seq, dim3(256), dim3(512), 0, stream,
                     inp, tgt, enc_bih, enc_bhh, dec_bih, dec_bhh,
                     lin1_b, lin2_w, lin2_b, wb, out);
}

// Round 11
// 768.562 us; speedup vs baseline: 1.2245x; 1.2245x over previous
//
#include <hip/hip_runtime.h>

// ---------------- constants ----------------
#define T_ENC 64
#define T_DEC 99

// fp8 e4m3 weight workspace (BYTES), fragment-permuted, uniform 6 slots/layer:
// phase blob = 4 layers x 6 slots; slot s: 0..2 = h-side gates r/z/n, 3..5 = x-side
// gates r/z/n.
// Gate weights pre-scaled at convert time: r/z by log2(e), n by 2*log2(e) ->
// every epilogue exp is ONE v_exp_f32.
// R9 lesson chain: inline-asm v_exp_f32 = TRANS result-use hazard invisible to
// compiler -> NaN (R7). libm exp2f() = OCML denormal-fixup wrapper, +4 VALU
// ops/call -> VALUBusy 54->62%, dur +142us (R8). The correct tool is
// __builtin_amdgcn_exp2f: raw v_exp_f32, hazard handled by the scheduler,
// fneg folded into the src modifier.
// MX K=128 slot layout (all slots EXCEPT layer-0 x-side):
//   slot[w][lane][b] (8*64*32 = 16384 BYTES): byte b (0..31) of lane (quad,ln) =
//   W[g*128 + w*16 + ln][quad*32 + b]   (scaled 16x16x128 B-layout, 32 B/lane)
// OLD K=32 layout ONLY for layer-0 x-side (wih0 zero-padded, ks=0 only):
//   slot[w][ks][lane][e]: byte e of lane = W[g*128+w*16+ln][ks*32+quad*8+e]
#define SLOT    16384
#define PH_BLOB 393216          // 24 slots
#define O_LIN1  786432          // 1 slot (lin1 B-frags, UNSCALED)
#define W_TOTAL 802816

#define L2E  1.4426950408889634f
#define L2E2 2.8853900817779268f

// output layout (f32 elements)
#define DEC_OUT_OFF 0
#define DEC_HID_OFF 1638400
#define ENC_OUT_OFF 3735552
#define ENC_HID_OFF 37289984
#define LOSS_OFF    39387136

typedef float f32x4 __attribute__((ext_vector_type(4)));
typedef int   v8i  __attribute__((ext_vector_type(8)));
typedef long  v4l  __attribute__((ext_vector_type(4)));

__device__ __forceinline__ v8i as8i(v4l x) {
  union { v4l l; v8i i; } u; u.l = x; return u.i;
}

// Empty-asm register tie: forces the loaded weight fragments to stay resident
// (R1 lesson: without it the compiler sank the loads into the t-loop).
__device__ __forceinline__ void keep(v4l &x) { asm volatile("" : "+v"(x)); }
__device__ __forceinline__ void keep(long &x) { asm volatile("" : "+v"(x)); }

// Raw hardware 2^x: one v_exp_f32, compiler-known (hazard-safe), fneg foldable.
#if __has_builtin(__builtin_amdgcn_exp2f)
__device__ __forceinline__ float exp2raw(float x) { return __builtin_amdgcn_exp2f(x); }
#else
extern "C" __device__ float __ocml_native_exp2_f32(float);
__device__ __forceinline__ float exp2raw(float x) { return __ocml_native_exp2_f32(x); }
#endif

// non-scaled K=32 fp8 MFMA (layer-0 x-side only)
#define MFMA8(a, b, c) __builtin_amdgcn_mfma_f32_16x16x32_fp8_fp8((a), (b), (c), 0, 0, 0)
// MX-scaled K=128 fp8 MFMA, scale byte 0x7F (=2^0) on both operands, fmt 0 = e4m3
#define MFMAS(a, b, c) \
  __builtin_amdgcn_mfma_scale_f32_16x16x128_f8f6f4(as8i(a), as8i(b), (c), 0, 0, 0, 127, 0, 127)

__device__ __forceinline__ unsigned f2fp8pk(float a, float b) {
  return (unsigned)__builtin_amdgcn_cvt_pk_fp8_f32(a, b, 0, false);
}

// ---------------- weight fp32 -> fp8 fragment-permute (+log2e baking) ----------
__device__ __forceinline__ float cw_value(int i,
    const float* ewih0, const float* ewhh0, const float* ewih, const float* ewhh,
    const float* dwih0, const float* dwhh0, const float* dwih, const float* dwhh,
    const float* lin1w) {
  if (i < O_LIN1) {
    const int ph = i / PH_BLOB;
    const int li = i % PH_BLOB;
    const float* wih0 = ph ? dwih0 : ewih0;
    const float* whh0 = ph ? dwhh0 : ewhh0;
    const float* wih  = ph ? dwih  : ewih;
    const float* whh  = ph ? dwhh  : ewhh;
    const int l = li / (6 * SLOT);
    const int r6 = li % (6 * SLOT);
    const int s = r6 / SLOT, r = r6 % SLOT;
    const int g = (s < 3) ? s : (s - 3);
    const float sc = (g == 2) ? L2E2 : L2E;   // n gate folds tanh's *2 too
    if (s >= 3 && l == 0) {
      const int w = r >> 11, ks = (r >> 9) & 3, lane = (r >> 3) & 63, e = r & 7;
      const int quad = lane >> 4, ln = lane & 15;
      const int row = g * 128 + w * 16 + ln;
      const int col = ks * 32 + quad * 8 + e;
      return (col < 4) ? sc * wih0[row * 4 + col] : 0.f;
    } else {
      const int w = r >> 11, lane = (r >> 5) & 63, b = r & 31;
      const int quad = lane >> 4, ln = lane & 15;
      const int row = g * 128 + w * 16 + ln;
      const int col = quad * 32 + b;
      return sc * ((s < 3) ? ((l == 0) ? whh0[row * 128 + col]
                                       : whh[(l - 1) * 49152 + row * 128 + col])
                           : wih[(l - 1) * 49152 + row * 128 + col]);
    }
  } else {
    const int r = i - O_LIN1;
    const int w = r >> 11, lane = (r >> 5) & 63, b = r & 31;
    const int quad = lane >> 4, ln = lane & 15;
    return lin1w[(w * 16 + ln) * 128 + quad * 32 + b];
  }
}

__global__ void convert_weights(const float* __restrict__ ewih0, const float* __restrict__ ewhh0,
                                const float* __restrict__ ewih, const float* __restrict__ ewhh,
                                const float* __restrict__ dwih0, const float* __restrict__ dwhh0,
                                const float* __restrict__ dwih, const float* __restrict__ dwhh,
                                const float* __restrict__ lin1w, unsigned char* __restrict__ wb,
                                float* __restrict__ out) {
  const int gid = blockIdx.x * 256 + threadIdx.x;
  if (gid == 0) out[LOSS_OFF] = 0.f;
  const int i0 = gid * 4;
  if (i0 >= W_TOTAL) return;
  unsigned w = 0;
#pragma unroll
  for (int k = 0; k < 4; k++) {
    float v = cw_value(i0 + k, ewih0, ewhh0, ewih, ewhh, dwih0, dwhh0, dwih, dwhh, lin1w);
    w |= (f2fp8pk(v, v) & 0xFFu) << (k * 8);
  }
  *(unsigned*)(wb + i0) = w;
}

// ---------------- main persistent kernel ----------------
// grid = 256 blocks (M=16 batch rows, 1 block/CU), block = 512 threads (8 waves).
// Layer-wavefront (R3): cells (t,l) on anti-diagonal d=t+l in ONE barrier
// interval (171 intervals). Trans diet (R6 math, R9 raw-builtin exp):
//  (a) log2e baked into weights/biases -> each exp is ONE v_exp_f32
//  (b) r/z reciprocals paired per element: 2 rcp -> 1 rcp + 3 mul
//      (overflow-safe: |ar|,|az| <= ~35 -> Ar*Az <= 2^70 finite)
//  (c) n reciprocals paired across element pairs; en clamped <= 1e15
//      (finite + NaN-killing: fminf(NaN,1e15)=1e15; saturates tanh to -1 exactly)
// Trans/element: 6 -> 4.5, with NO wrapper VALU overhead (R8 lesson).
__global__ __launch_bounds__(512, 2) void gru_seq2seq(
    const float* __restrict__ inp, const float* __restrict__ tgt,
    const float* __restrict__ enc_bih, const float* __restrict__ enc_bhh,
    const float* __restrict__ dec_bih, const float* __restrict__ dec_bhh,
    const float* __restrict__ lin1_b, const float* __restrict__ lin2_w,
    const float* __restrict__ lin2_b, const unsigned char* __restrict__ wb,
    float* __restrict__ out) {
  const int tid = threadIdx.x;
  const int wave = tid >> 6;
  const int lane = tid & 63;
  const int ln = lane & 15;
  const int quad = lane >> 4;
  const int b0 = blockIdx.x * 16;
  const int j = (wave << 4) + ln;

  __shared__ __align__(16) unsigned char hb8[2][4][16][128];  // fp8 h [parity][l][m][swz k]
  __shared__ __align__(16) unsigned char xt8[2][16][128];     // fp8 x-tile (K=128 padded)
  __shared__ __align__(16) unsigned char trash[2048];         // sink for invalid-cell writes
  __shared__ float bsum[4][2][128];                           // (bih+bhh)*L2E for r,z
  __shared__ float bnn[4][2][128];                            // bin*L2E2, bhn*L2E2
  __shared__ float lin1bs[128];
  __shared__ __align__(16) float lin2ws[4][132];
  __shared__ float lin2bs[4];
  __shared__ __align__(16) float relu_s[2][16][132];          // double-buffered (pipeline stage)

  for (int i = tid; i < 2 * 4 * 16 * 128; i += 512) ((unsigned char*)hb8)[i] = 0;
  for (int i = tid; i < 2 * 16 * 128; i += 512) ((unsigned char*)xt8)[i] = 0;
  if (tid < 128) lin1bs[tid] = lin1_b[tid];
  { int e = tid >> 7, k = tid & 127; lin2ws[e][k] = lin2_w[e * 128 + k]; }
  if (tid < 4) lin2bs[tid] = lin2_b[tid];

  // fp32 h master, register-resident (thread-private: m=quad*4+r, col j)
  float hreg[4][4];
#pragma unroll
  for (int l = 0; l < 4; l++)
#pragma unroll
    for (int r = 0; r < 4; r++) hreg[l][r] = 0.f;

  float loss_local = 0.f;

  // decoder_output[:, 0, :] = inp[:, 0, :]
  if (tid < 64) {
    int m = tid >> 2, e = tid & 3;
    out[DEC_OUT_OFF + (b0 + m) * 400 + e] = inp[(b0 + m) * 256 + e];
  }

  const int fofs32 = wave * 2048 + lane * 32;
  const int fofs8  = wave * 2048 + lane * 8;

  v4l w1v = *(const v4l*)(wb + O_LIN1 + fofs32);
  keep(w1v);

#pragma unroll 1
  for (int ph = 0; ph < 2; ph++) {
    const float* bih = ph ? dec_bih : enc_bih;
    const float* bhh = ph ? dec_bhh : enc_bhh;
    {  // per-phase biases -> LDS (pre-scaled: r/z by L2E, n by L2E2)
      int l = tid >> 7, jj = tid & 127;
      bsum[l][0][jj] = L2E * (bih[l * 384 + jj] + bhh[l * 384 + jj]);
      bsum[l][1][jj] = L2E * (bih[l * 384 + 128 + jj] + bhh[l * 384 + 128 + jj]);
      bnn[l][0][jj] = L2E2 * bih[l * 384 + 256 + jj];
      bnn[l][1][jj] = L2E2 * bhh[l * 384 + 256 + jj];
    }
    // step-0 input for both phases: inp[:, 0, :] -> xt8[0] (read at d=0, p=0)
    if (tid < 64) {
      int m = tid >> 2, e = tid & 3;
      xt8[0][m][(m << 3) | e] =
          (unsigned char)(f2fp8pk(inp[(b0 + m) * 256 + e], 0.f) & 0xFF);
    }
    __syncthreads();

    // ---- per-phase REGISTER-RESIDENT fp8 weights (K=128 frags) ----
    const unsigned char* PB = wb + ph * PH_BLOB;
    v4l whv[4][3];  // h-side [l][gate]
    v4l wxv[3][3];  // x-side [l-1][gate], layers 1..3
    long wx0f[3];   // x-side layer 0, OLD layout ks=0 only
#pragma unroll
    for (int l = 0; l < 4; l++)
#pragma unroll
      for (int g = 0; g < 3; g++) {
        whv[l][g] = *(const v4l*)(PB + l * 6 * SLOT + g * SLOT + fofs32);
        keep(whv[l][g]);
      }
#pragma unroll
    for (int l = 1; l < 4; l++)
#pragma unroll
      for (int g = 0; g < 3; g++) {
        wxv[l - 1][g] = *(const v4l*)(PB + l * 6 * SLOT + (3 + g) * SLOT + fofs32);
        keep(wxv[l - 1][g]);
      }
#pragma unroll
    for (int g = 0; g < 3; g++) {
      wx0f[g] = *(const long*)(PB + (3 + g) * SLOT + fofs8);
      keep(wx0f[g]);
    }

    const float l1b = lin1bs[j];
    const int T = ph ? T_DEC : T_ENC;
    const int Dtot = ph ? (T_DEC + 5) : (T_ENC + 3);

#pragma unroll 1
    for (int d = 0; d < Dtot; d++) {
      const int p = d & 1;
      const unsigned char* hprev = &hb8[1 - p][0][0][0];  // [l][16][128] blob, parity 1-p

      // ======== 4 wavefront cells, one basic block, lazy A-frag reuse ========
      v4l Fprev;  // h-frags of layer l-1 (== x-side frags of cell l)
      long x0f;   // layer-0 x frag
      {
        const unsigned char* xb = &xt8[p][0][0] + ln * 128;
        x0f = *(const long*)(xb + ((quad ^ ln) << 3));
      }
#pragma unroll
      for (int l = 0; l < 4; l++) {
        const int t = d - l;
        const bool valid = (t >= 0) && (t < T);
        // load this layer's h-frags (reused as next cell's x-frags)
        v4l Fl;
        {
          const unsigned char* ahb = hprev + l * 2048 + ln * 128;
#pragma unroll
          for (int i4 = 0; i4 < 4; i4++)
            Fl[i4] = *(const long*)(ahb + ((((quad * 4 + i4) ^ ln) << 3)));
        }
        // bias-seeded accumulators (biases pre-scaled by L2E/L2E2)
        const float brl = bsum[l][0][j], bzl = bsum[l][1][j];
        const float binl = bnn[l][0][j], bhnl = bnn[l][1][j];
        f32x4 ar  = {brl, brl, brl, brl};
        f32x4 az  = {bzl, bzl, bzl, bzl};
        f32x4 ani = {binl, binl, binl, binl};
        f32x4 anh = {bhnl, bhnl, bhnl, bhnl};
        // h-side
        ar  = MFMAS(Fl, whv[l][0], ar);
        az  = MFMAS(Fl, whv[l][1], az);
        anh = MFMAS(Fl, whv[l][2], anh);
        // x-side
        if (l > 0) {
          ar  = MFMAS(Fprev, wxv[l - 1][0], ar);
          az  = MFMAS(Fprev, wxv[l - 1][1], az);
          ani = MFMAS(Fprev, wxv[l - 1][2], ani);
        } else {
          ar  = MFMA8(x0f, wx0f[0], ar);
          az  = MFMA8(x0f, wx0f[1], az);
          ani = MFMA8(x0f, wx0f[2], ani);
        }
        Fprev = Fl;  // becomes x-side of cell l+1 (and lin1 input at l=3)
        // ---- epilogue: trans-lean gates (4.5 trans/element), raw v_exp ----
        float zg4[4], en4[4], hnv[4];
#pragma unroll
        for (int r = 0; r < 4; r++) {
          const float er = exp2raw(-ar[r]);     // e^-x (weights carry log2e)
          const float ez = exp2raw(-az[r]);
          const float Ar = 1.f + er, Az = 1.f + ez;
          const float R = __builtin_amdgcn_rcpf(Ar * Az);   // <= 2^70: finite
          const float rg = Az * R;              // 1/(1+er)
          zg4[r] = Ar * R;                      // 1/(1+ez)
          const float xn = ani[r] + rg * anh[r];
          en4[r] = fminf(exp2raw(-xn), 1e15f);  // e^-2y; clamp = overflow+NaN guard
        }
#pragma unroll
        for (int rp = 0; rp < 2; rp++) {
          const float e0 = en4[2 * rp], e1 = en4[2 * rp + 1];
          const float D0 = 1.f + e0, D1 = 1.f + e1;
          const float R = __builtin_amdgcn_rcpf(D0 * D1);   // <= 1.2e30: finite
          const float ng0 = (1.f - e0) * (D1 * R);
          const float ng1 = (1.f - e1) * (D0 * R);
          {
            const int r = 2 * rp;
            const float hp = hreg[l][r];
            const float hn = ng0 + zg4[r] * (hp - ng0);
            hreg[l][r] = valid ? hn : hp;
            hnv[r] = hn;
          }
          {
            const int r = 2 * rp + 1;
            const float hp = hreg[l][r];
            const float hn = ng1 + zg4[r] * (hp - ng1);
            hreg[l][r] = valid ? hn : hp;
            hnv[r] = hn;
          }
        }
        {  // fp8 re-quantized h -> hb8[p][l], or trash when cell invalid
          unsigned pkA = f2fp8pk(hnv[0], hnv[1]);
          unsigned pkB = f2fp8pk(hnv[2], hnv[3]);
          unsigned char* hw = valid ? &hb8[p][l][0][0] : &trash[0];
          const int m0 = quad * 4;
#pragma unroll
          for (int r = 0; r < 4; r++) {
            const int m = m0 + r;
            const unsigned pk = (r < 2) ? pkA : pkB;
            hw[m * 128 + ((((j >> 3) ^ m) << 3) | (j & 7))] =
                (unsigned char)((pk >> ((r & 1) * 8)) & 0xFF);
          }
        }
      }  // cells

      // ======== deferred global stores (read hreg; uniform guards) ========
      if (!ph) {
        const int t3 = d - 3;  // cell (t3,3) finished this interval
        if (t3 >= 0) {
#pragma unroll
          for (int r = 0; r < 4; r++) {
            const int m = quad * 4 + r;
            out[ENC_OUT_OFF + ((b0 + m) * 64 + t3) * 128 + j] = hreg[3][r];
          }
        }
#pragma unroll
        for (int ll = 0; ll < 4; ll++)
          if (d == T_ENC - 1 + ll) {  // cell (63,ll) finished this interval
#pragma unroll
            for (int r = 0; r < 4; r++) {
              const int m = quad * 4 + r;
              out[ENC_HID_OFF + (ll * 4096 + b0 + m) * 128 + j] = hreg[ll][r];
            }
          }
      } else {
#pragma unroll
        for (int ll = 0; ll < 4; ll++)
          if (d == T_DEC - 1 + ll) {  // cell (98,ll) finished this interval
#pragma unroll
            for (int r = 0; r < 4; r++) {
              const int m = quad * 4 + r;
              out[DEC_HID_OFF + (ll * 4096 + b0 + m) * 128 + j] = hreg[ll][r];
            }
          }
      }

      // ======== x prefetch for step d+1 (read at interval d+1 from xt8[1-p]) ========
      if ((d + 1) < T && tid < 64) {
        int m = tid >> 2, e = tid & 3;
        float xv = ph ? tgt[(b0 + m) * 400 + (d + 1) * 4 + e]
                      : inp[(b0 + m) * 256 + (d + 1) * 4 + e];
        xt8[1 - p][m][(m << 3) | e] = (unsigned char)(f2fp8pk(xv, 0.f) & 0xFF);
      }

      // ======== decoder pipeline tails: lin1 (stage d-4), lin2 (stage d-5) ========
      if (ph) {
        const int t1 = d - 4;
        if (t1 >= 0 && t1 < T_DEC) {
          // h3[t1] written by cell (t1,3) at interval d-1 -> parity 1-p == Fprev
          f32x4 a1 = {l1b, l1b, l1b, l1b};
          a1 = MFMAS(Fprev, w1v, a1);
#pragma unroll
          for (int r = 0; r < 4; r++) {
            const int m = quad * 4 + r;
            const float v = a1[r];
            relu_s[p][m][j] = v > 0.f ? v : 0.f;
          }
        }
        const int t2 = d - 5;
        if (t2 >= 0) {  // t2 <= 98 guaranteed (d <= 103)
          const int m2 = tid >> 5, e2 = (tid >> 3) & 3, kg = tid & 7;
          const float4* rs = (const float4*)&relu_s[1 - p][m2][kg * 16];
          const float4* ws = (const float4*)&lin2ws[e2][kg * 16];
          float a0 = 0.f, a1p = 0.f;
#pragma unroll
          for (int q = 0; q < 4; q += 2) {
            float4 r0 = rs[q], w0 = ws[q];
            float4 r1 = rs[q + 1], w1 = ws[q + 1];
            a0 += r0.x * w0.x + r0.y * w0.y + r0.z * w0.z + r0.w * w0.w;
            a1p += r1.x * w1.x + r1.y * w1.y + r1.z * w1.z + r1.w * w1.w;
          }
          float acc = a0 + a1p;
          acc += __shfl_down(acc, 4);
          acc += __shfl_down(acc, 2);
          acc += __shfl_down(acc, 1);
          if (kg == 0) {
            acc += lin2bs[e2];
            const int oidx = (b0 + m2) * 400 + (t2 + 1) * 4 + e2;
            out[DEC_OUT_OFF + oidx] = acc;
            const float d2 = acc - tgt[oidx];
            loss_local += d2 * d2;
          }
        }
      }

      __syncthreads();
    }  // d
  }  // phase

  // ---- loss reduction ----
  loss_local *= (1.f / 16384.f);  // mean over (B=4096, E=4)
#pragma unroll
  for (int off = 32; off; off >>= 1) loss_local += __shfl_down(loss_local, off);
  if (lane == 0) atomicAdd(&out[LOSS_OFF], loss_local);
}

// ---------------- launch ----------------
extern "C" void kernel_launch(void* const* d_in, const int* in_sizes, int n_in,
                              void* d_out, int out_size, void* d_ws, size_t ws_size,
                              hipStream_t stream) {
  const float* inp      = (const float*)d_in[0];
  const float* tgt      = (const float*)d_in[1];
  const float* enc_wih0 = (const float*)d_in[2];
  const float* enc_whh0 = (const float*)d_in[3];
  const float* enc_wih  = (const float*)d_in[4];
  const float* enc_whh  = (const float*)d_in[5];
  const float* enc_bih  = (const float*)d_in[6];
  const float* enc_bhh  = (const float*)d_in[7];
  const float* dec_wih0 = (const float*)d_in[8];
  const float* dec_whh0 = (const float*)d_in[9];
  const float* dec_wih  = (const float*)d_in[10];
  const float* dec_whh  = (const float*)d_in[11];
  const float* dec_bih  = (const float*)d_in[12];
  const float* dec_bhh  = (const float*)d_in[13];
  const float* lin1_w   = (const float*)d_in[14];
  const float* lin1_b   = (const float*)d_in[15];
  const float* lin2_w   = (const float*)d_in[16];
  const float* lin2_b   = (const float*)d_in[17];
  unsigned char* wb = (unsigned char*)d_ws;
  float* out = (float*)d_out;

  hipLaunchKernelGGL(convert_weights, dim3((W_TOTAL / 4 + 255) / 256), dim3(256), 0, stream,
                     enc_wih0, enc_whh0, enc_wih, enc_whh, dec_wih0, dec_whh0, dec_wih,
                     dec_whh, lin1_w, wb, out);
  hipLaunchKernelGGL(gru_seq2seq, dim3(256), dim3(512), 0, stream,
                     inp, tgt, enc_bih, enc_bhh, dec_bih, dec_bhh,
                     lin1_b, lin2_w, lin2_b, wb, out);
}